// Round 14
// baseline (23.169 us; speedup 1.0000x reference)
//
#include <hip/hip_runtime.h>

#define D_MAX   50
#define T_DIM   51
#define B_DIM   16
#define P_DIM   2048
#define Q_DIM   2048
#define TSTRIDE 72            // bytes per t-row: 64 used + 8 skew; 18 dwords,
                              // gcd(18,32)=2 -> 16 start-bank classes (vs 8 at 80)
#define PBY     3688          // bytes per p-row: 51*72=3672 pad to 8-mult; 922 dwords,
                              // 922 mod 32 = 26 -> per-p rotation + 2-way-free pack writes
#define PSPAN   32            // p's per block -> LDS 118,016 B
#define NPBLK   (P_DIM / PSPAN)        // 64
#define QB      512
#define PCHK    8             // W/DR pipeline chunk (4 chunks of 8 p)

// ws layout: partial ushort(bf16) [NPBLK][B][Q] = 4 MiB

// d = taps.lo*cw.lo + taps.hi*cw.hi + acc   (bf16 pair dot, f32 accumulate)
__device__ __forceinline__ float dot2bf(unsigned taps, unsigned cw, float acc) {
    float d;
    asm("v_dot2_f32_bf16 %0, %1, %2, %3" : "=v"(d) : "v"(taps), "v"(cw), "v"(acc));
    return d;
}
__device__ __forceinline__ unsigned pack_bf16x2(float lo, float hi) {
    unsigned r;
    asm("v_cvt_pk_bf16_f32 %0, %1, %2" : "=v"(r) : "v"(lo), "v"(hi));
    return r;
}
__device__ __forceinline__ unsigned short rne_bf16(float v) {
    unsigned x = __float_as_uint(v);
    x += 0x7fffu + ((x >> 16) & 1u);
    return (unsigned short)(x >> 16);
}

#define PREFETCH(wArr, xArr, cc)                                            \
    _Pragma("unroll")                                                       \
    for (int j = 0; j < PCHK; ++j) {                                        \
        wArr[j] = Wq[(size_t)(p0 + (cc) * PCHK + j) * Q_DIM];               \
        xArr[j] = Dq[(size_t)(p0 + (cc) * PCHK + j) * Q_DIM];               \
    }

// 64B row read as 8x uint2 (8B-aligned; rows are only 8B-aligned at stride 72).
#define COMPUTE8(wArr, xArr, cc)                                            \
    _Pragma("unroll")                                                       \
    for (int jj = 0; jj < PCHK; ++jj) {                                     \
        const int p = (cc) * PCHK + jj;                                     \
        const float w = wArr[jj], x = xArr[jj];                             \
        const float d = 50.f / (1.f + __expf(-x));                          \
        const int df = min((int)d, D_MAX);                                  \
        const float a  = d - (float)df;                                     \
        const float wa = w * a;                                             \
        const unsigned cw = pack_bf16x2(w - wa, wa);                        \
        const char* rb = lds + p * PBY + df * TSTRIDE;                      \
        const uint2 u0 = *(const uint2*)(rb);                               \
        const uint2 u1 = *(const uint2*)(rb + 8);                           \
        const uint2 u2 = *(const uint2*)(rb + 16);                          \
        const uint2 u3 = *(const uint2*)(rb + 24);                          \
        const uint2 u4 = *(const uint2*)(rb + 32);                          \
        const uint2 u5 = *(const uint2*)(rb + 40);                          \
        const uint2 u6 = *(const uint2*)(rb + 48);                          \
        const uint2 u7 = *(const uint2*)(rb + 56);                          \
        acc[0]  = dot2bf(u0.x, cw, acc[0]);                                 \
        acc[1]  = dot2bf(u0.y, cw, acc[1]);                                 \
        acc[2]  = dot2bf(u1.x, cw, acc[2]);                                 \
        acc[3]  = dot2bf(u1.y, cw, acc[3]);                                 \
        acc[4]  = dot2bf(u2.x, cw, acc[4]);                                 \
        acc[5]  = dot2bf(u2.y, cw, acc[5]);                                 \
        acc[6]  = dot2bf(u3.x, cw, acc[6]);                                 \
        acc[7]  = dot2bf(u3.y, cw, acc[7]);                                 \
        acc[8]  = dot2bf(u4.x, cw, acc[8]);                                 \
        acc[9]  = dot2bf(u4.y, cw, acc[9]);                                 \
        acc[10] = dot2bf(u5.x, cw, acc[10]);                                \
        acc[11] = dot2bf(u5.y, cw, acc[11]);                                \
        acc[12] = dot2bf(u6.x, cw, acc[12]);                                \
        acc[13] = dot2bf(u6.y, cw, acc[13]);                                \
        acc[14] = dot2bf(u7.x, cw, acc[14]);                                \
        acc[15] = dot2bf(u7.y, cw, acc[15]);                                \
    }

// Fused kernel (R13 structure, 72B skew): block = 512 q-lanes, 32 p.
// Phase 1: pack bf16 tap-pair image from buf into LDS. Phase 2: 4 chunks
// of 8 p, W/DR register-double-buffered; per p: sigmoid once, 8x uint2 LDS
// row read (16 start-bank classes), 16 v_dot2. Epilogue: bf16 partials.
__global__ __launch_bounds__(512, 2) void dsl_fused_kernel(
    const float* __restrict__ buf, const float* __restrict__ W,
    const float* __restrict__ DR, unsigned short* __restrict__ partial) {
    __shared__ char lds[PSPAN * PBY];   // 118,016 B
    const int tid = threadIdx.x;
    // 256 blocks = 4 q-cols x 64 p-slices; the 4 blocks of one p-slice are
    // 64 apart in dispatch order -> same XCD (64 % 8 == 0) -> shared L2 buf.
    const int i  = blockIdx.x;
    const int xq = i >> 6;                            // 0..3 q-column
    const int yp = ((i & 7) << 3) | ((i >> 3) & 7);   // bijective on [0,64)
    const int q  = xq * QB + tid;
    const int p0 = yp * PSPAN;

    // ---- phase 1: pack. thread = (b = tid>>5, p = tid&31)
    {
        const int bb = tid >> 5, pl = tid & 31;
        const float* src = buf + (size_t)bb * (T_DIM * P_DIM) + p0 + pl;
        float v[T_DIM + 1];
#pragma unroll
        for (int t = 0; t < T_DIM; ++t)
            v[t] = src[(size_t)t * P_DIM];    // 2 x 128B segments per t per wave
        v[T_DIM] = 0.f;
        char* wb = lds + pl * PBY + bb * 4;
#pragma unroll
        for (int t = 0; t < T_DIM; ++t)       // row t holds (v[t], v[t+1])
            *(unsigned*)(wb + t * TSTRIDE) = pack_bf16x2(v[t], v[t + 1]);
    }

    // ---- chunk-0 W/DR preload only (rest pipelined inside compute)
    const float* Wq = W + q;
    const float* Dq = DR + q;
    float wA[PCHK], xA[PCHK], wB[PCHK], xB[PCHK];
    PREFETCH(wA, xA, 0)
    __syncthreads();

    // ---- phase 2: compute, register-double-buffered W/DR stream
    float acc[B_DIM];
#pragma unroll
    for (int b = 0; b < B_DIM; ++b) acc[b] = 0.f;

    PREFETCH(wB, xB, 1)       // chunk-1 loads fly during chunk-0 compute
    COMPUTE8(wA, xA, 0)
    PREFETCH(wA, xA, 2)
    COMPUTE8(wB, xB, 1)
    PREFETCH(wB, xB, 3)
    COMPUTE8(wA, xA, 2)
    COMPUTE8(wB, xB, 3)

    unsigned short* dst = partial + (size_t)yp * (B_DIM * Q_DIM) + q;
#pragma unroll
    for (int b = 0; b < B_DIM; ++b)
        dst[(size_t)b * Q_DIM] = rne_bf16(acc[b]);    // coalesced along q
}

// Reduce: sum NPBLK bf16 partials in f32; block = 64 outputs x 4 c-waves.
__global__ __launch_bounds__(256) void dsl_reduce_kernel(
    const unsigned short* __restrict__ partial, float* __restrict__ out) {
    __shared__ float lds[4][64];
    const int j = threadIdx.x & 63, w = threadIdx.x >> 6;
    const int idx = blockIdx.x * 64 + j;              // idx = b*Q + q
    float s = 0.f;
    for (int c = w; c < NPBLK; c += 4) {
        const unsigned u = partial[(size_t)c * (B_DIM * Q_DIM) + idx];
        s += __uint_as_float(u << 16);
    }
    lds[w][j] = s;
    __syncthreads();
    if (w == 0)
        out[idx] = lds[0][j] + lds[1][j] + lds[2][j] + lds[3][j];
}

extern "C" void kernel_launch(void* const* d_in, const int* in_sizes, int n_in,
                              void* d_out, int out_size, void* d_ws, size_t ws_size,
                              hipStream_t stream) {
    const float* buf = (const float*)d_in[0];   // [B, T, P]
    const float* W   = (const float*)d_in[1];   // [P, Q]
    const float* DR  = (const float*)d_in[2];   // [P, Q]
    float* out = (float*)d_out;                 // [B, Q]

    unsigned short* partial = (unsigned short*)d_ws;  // [NPBLK][B][Q], 4 MiB

    hipLaunchKernelGGL(dsl_fused_kernel, dim3(256), dim3(512), 0, stream,
                       buf, W, DR, partial);
    hipLaunchKernelGGL(dsl_reduce_kernel, dim3((B_DIM * Q_DIM) / 64), dim3(256), 0, stream,
                       partial, out);
}